// Round 2
// baseline (1381.168 us; speedup 1.0000x reference)
//
#include <hip/hip_runtime.h>
#include <math.h>

constexpr int B_  = 32;
constexpr int N_  = 200000;
constexpr int XSZ = 256;
constexpr int IMG_ELEMS = B_ * XSZ * XSZ;   // 2097152
constexpr int PADS = 257;                   // SoA LDS row stride (floats)

// workspace offsets (bytes)
constexpr size_t OFF_PART = 0;                                   // 256*72*4 = 73728
constexpr size_t OFF_H    = 73728;                               // 32*8*4
constexpr size_t OFF_R    = OFF_H + 1024;                        // 32*9*4
constexpr size_t OFF_IMG  = 131072;                              // 8 MB
constexpr size_t OFF_TMP  = OFF_IMG + (size_t)IMG_ELEMS * 4;     // 8 MB
constexpr size_t OFF_FC   = OFF_TMP + (size_t)IMG_ELEMS * 4;     // 32 MB (float2)

__device__ __forceinline__ int rev8(int x) { return (int)(__brev((unsigned)x) >> 24); }

// ---------------- T reduction: T[j,i,k] = sum_n coords[n,j] * W1[3n+i,k] ----------------
__global__ __launch_bounds__(256) void k_reduceT(const float* __restrict__ coords,
                                                 const float* __restrict__ W1,
                                                 float* __restrict__ partial) {
  float acc[72];
  #pragma unroll
  for (int t = 0; t < 72; ++t) acc[t] = 0.f;
  int idx = blockIdx.x * 256 + threadIdx.x;
  for (int n = idx; n < N_; n += 256 * 256) {
    float c0 = coords[n * 3 + 0], c1 = coords[n * 3 + 1], c2 = coords[n * 3 + 2];
    const float4* w4 = reinterpret_cast<const float4*>(W1 + (size_t)n * 24);
    #pragma unroll
    for (int i = 0; i < 3; ++i) {
      float4 wa = w4[i * 2 + 0], wb = w4[i * 2 + 1];
      float wv[8] = {wa.x, wa.y, wa.z, wa.w, wb.x, wb.y, wb.z, wb.w};
      #pragma unroll
      for (int k = 0; k < 8; ++k) {
        acc[i * 8 + k]      += c0 * wv[k];
        acc[24 + i * 8 + k] += c1 * wv[k];
        acc[48 + i * 8 + k] += c2 * wv[k];
      }
    }
  }
  #pragma unroll
  for (int t = 0; t < 72; ++t) {
    float v = acc[t];
    for (int off = 32; off > 0; off >>= 1) v += __shfl_down(v, off, 64);
    acc[t] = v;
  }
  __shared__ float sred[4][72];
  int lane = threadIdx.x & 63, wv_ = threadIdx.x >> 6;
  if (lane == 0) {
    #pragma unroll
    for (int t = 0; t < 72; ++t) sred[wv_][t] = acc[t];
  }
  __syncthreads();
  if (threadIdx.x < 72) {
    int t = threadIdx.x;
    partial[blockIdx.x * 72 + t] = sred[0][t] + sred[1][t] + sred[2][t] + sred[3][t];
  }
}

// ---------------- per-batch: finalize T, rotation matrices, MLP head ----------------
__global__ __launch_bounds__(128) void k_batch(const float* __restrict__ partial,
                                               const float* __restrict__ rows,
                                               const float* __restrict__ b1,
                                               const float* __restrict__ Wh,
                                               const float* __restrict__ bh,
                                               float* __restrict__ hbuf,
                                               float* __restrict__ Rbuf) {
  __shared__ float T[72];
  int tid = threadIdx.x;
  if (tid < 72) {
    double s = 0.0;
    for (int i = 0; i < 256; ++i) s += (double)partial[i * 72 + tid];
    T[tid] = (float)s;
  }
  __syncthreads();
  if (tid < B_) {
    int b = tid;
    float al = rows[b * 3 + 0], be = rows[b * 3 + 1], ga = rows[b * 3 + 2];
    float sa, ca, sb, cb, sg, cg;
    sincosf(al, &sa, &ca); sincosf(be, &sb, &cb); sincosf(ga, &sg, &cg);
    float R[3][3];
    R[0][0] = ca * cb * cg - sa * sg; R[0][1] = -ca * cb * sg - sa * cg; R[0][2] = ca * sb;
    R[1][0] = sa * cb * cg + ca * sg; R[1][1] = -sa * cb * sg + ca * cg; R[1][2] = sa * sb;
    R[2][0] = -sb * cg;               R[2][1] = sb * sg;                 R[2][2] = cb;
    float h[8];
    #pragma unroll
    for (int k = 0; k < 8; ++k) {
      float z = b1[k];
      #pragma unroll
      for (int i = 0; i < 3; ++i)
        #pragma unroll
        for (int j = 0; j < 3; ++j)
          z += R[i][j] * T[(j * 3 + i) * 8 + k];
      h[k] = sinf(30.f * z);
    }
    for (int l = 0; l < 3; ++l) {
      float nh[8];
      #pragma unroll
      for (int k2 = 0; k2 < 8; ++k2) {
        float z = bh[l * 8 + k2];
        #pragma unroll
        for (int k1 = 0; k1 < 8; ++k1) z += h[k1] * Wh[l * 64 + k1 * 8 + k2];
        nh[k2] = sinf(z);
      }
      #pragma unroll
      for (int k = 0; k < 8; ++k) h[k] = nh[k];
    }
    #pragma unroll
    for (int k = 0; k < 8; ++k) hbuf[b * 8 + k] = h[k];
    #pragma unroll
    for (int i = 0; i < 3; ++i)
      #pragma unroll
      for (int j = 0; j < 3; ++j) Rbuf[b * 9 + i * 3 + j] = R[i][j];
  }
}

// ---------------- delta + bilinear scatter ----------------
__global__ __launch_bounds__(256) void k_scatter(const float* __restrict__ coords,
                                                 const float* __restrict__ W5,
                                                 const float* __restrict__ b5,
                                                 const float* __restrict__ hbuf,
                                                 const float* __restrict__ Rbuf,
                                                 const float* __restrict__ shifts,
                                                 float* __restrict__ img) {
  __shared__ float sh[B_][8];
  __shared__ float sR[B_][6];
  __shared__ float ss[B_][2];
  int tid = threadIdx.x;
  if (tid < B_) {
    #pragma unroll
    for (int k = 0; k < 8; ++k) sh[tid][k] = hbuf[tid * 8 + k];
    #pragma unroll
    for (int j = 0; j < 3; ++j) { sR[tid][j] = Rbuf[tid * 9 + j]; sR[tid][3 + j] = Rbuf[tid * 9 + 3 + j]; }
    ss[tid][0] = shifts[tid * 2]; ss[tid][1] = shifts[tid * 2 + 1];
  }
  __syncthreads();
  int n = blockIdx.x * 256 + tid;
  if (n >= N_) return;
  float c0 = coords[n * 3], c1 = coords[n * 3 + 1], c2 = coords[n * 3 + 2];
  float w5v[8];
  #pragma unroll
  for (int k = 0; k < 8; ++k) w5v[k] = W5[(size_t)k * N_ + n];
  float b5n = b5[n];
  for (int b = 0; b < B_; ++b) {
    float cx = sR[b][0] * c0 + sR[b][1] * c1 + sR[b][2] * c2;
    float cy = sR[b][3] * c0 + sR[b][4] * c1 + sR[b][5] * c2;
    float delta = b5n;
    #pragma unroll
    for (int k = 0; k < 8; ++k) delta += sh[b][k] * w5v[k];
    float px = cx * 100.f + 128.f - ss[b][0];
    float py = cy * 100.f + 128.f - ss[b][1];
    float x0f = floorf(px), y0f = floorf(py);
    float fx = px - x0f, fy = py - y0f;
    int x0 = (int)x0f, y0 = (int)y0f;
    float* im = img + (size_t)b * (XSZ * XSZ);
    float w00 = (1.f - fx) * (1.f - fy) * delta;
    float w10 = fx * (1.f - fy) * delta;
    float w01 = (1.f - fx) * fy * delta;
    float w11 = fx * fy * delta;
    if ((unsigned)x0 < XSZ && (unsigned)y0 < XSZ)                 unsafeAtomicAdd(&im[y0 * XSZ + x0], w00);
    if ((unsigned)(x0 + 1) < XSZ && (unsigned)y0 < XSZ)           unsafeAtomicAdd(&im[y0 * XSZ + x0 + 1], w10);
    if ((unsigned)x0 < XSZ && (unsigned)(y0 + 1) < XSZ)           unsafeAtomicAdd(&im[(y0 + 1) * XSZ + x0], w01);
    if ((unsigned)(x0 + 1) < XSZ && (unsigned)(y0 + 1) < XSZ)     unsafeAtomicAdd(&im[(y0 + 1) * XSZ + x0 + 1], w11);
  }
}

// ---------------- separable Gaussian blur (zero-padded SAME) ----------------
__device__ __forceinline__ float bwv(int i) {
  const float bw[7] = {0.004433048f, 0.054005582f, 0.242036226f, 0.399050280f,
                       0.242036226f, 0.054005582f, 0.004433048f};
  return bw[i];
}

__global__ __launch_bounds__(256) void k_blurV(const float* __restrict__ in, float* __restrict__ out) {
  int i = blockIdx.x * 256 + threadIdx.x;
  int x = i & 255;
  int y = (i >> 8) & 255;
  const float* p = in + (i & ~65535);
  float s = 0.f;
  #pragma unroll
  for (int d = -3; d <= 3; ++d) {
    int yy = y + d;
    if ((unsigned)yy < XSZ) s += bwv(d + 3) * p[(yy << 8) + x];
  }
  out[i] = s;
}

__global__ __launch_bounds__(256) void k_blurH(const float* __restrict__ in, float* __restrict__ out) {
  int i = blockIdx.x * 256 + threadIdx.x;
  int x = i & 255;
  float s = 0.f;
  #pragma unroll
  for (int d = -3; d <= 3; ++d) {
    int xx = x + d;
    if ((unsigned)xx < XSZ) s += bwv(d + 3) * in[i + d];
  }
  out[i] = s;
}

// ---------------- FFT helpers: 256-pt, SoA in LDS, stride PADS ----------------
// tw[k] = e^{-2*pi*i*k/256}
__device__ __forceinline__ void fft_dif_fwd(float* re, float* im, const float2* tw, int P, int tid) {
  for (int s = 7; s >= 0; --s) {
    __syncthreads();
    int half = 1 << s;
    for (int q = tid; q < (P << 7); q += 256) {
      int p = q >> 7, k = q & 127;
      int j = k & (half - 1);
      int i0 = ((k >> s) << (s + 1)) | j;
      int i1 = i0 + half;
      float* rp = re + p * PADS; float* ip = im + p * PADS;
      float ar = rp[i0], ai = ip[i0], br = rp[i1], bi = ip[i1];
      rp[i0] = ar + br; ip[i0] = ai + bi;
      float tr = ar - br, ti = ai - bi;
      float2 w = tw[j << (7 - s)];
      rp[i1] = tr * w.x - ti * w.y;
      ip[i1] = tr * w.y + ti * w.x;
    }
  }
  __syncthreads();
}

__device__ __forceinline__ void fft_dit_inv(float* re, float* im, const float2* tw, int P, int tid) {
  for (int s = 0; s <= 7; ++s) {
    __syncthreads();
    int half = 1 << s;
    for (int q = tid; q < (P << 7); q += 256) {
      int p = q >> 7, k = q & 127;
      int j = k & (half - 1);
      int i0 = ((k >> s) << (s + 1)) | j;
      int i1 = i0 + half;
      float* rp = re + p * PADS; float* ip = im + p * PADS;
      float2 w = tw[j << (7 - s)];               // conj -> (w.x, -w.y)
      float br = rp[i1], bi = ip[i1];
      float tr = br * w.x + bi * w.y;
      float ti = bi * w.x - br * w.y;
      float ar = rp[i0], ai = ip[i0];
      rp[i0] = ar + tr; ip[i0] = ai + ti;
      rp[i1] = ar - tr; ip[i1] = ai - ti;
    }
  }
  __syncthreads();
}

__device__ __forceinline__ void tw_init(float2* tw, int tid) {
  for (int k = tid; k < 128; k += 256) {
    float s_, c_;
    sincosf(-6.2831853071795864769f * (float)k / 256.0f, &s_, &c_);
    tw[k] = make_float2(c_, s_);
  }
}

// F1: row FFT (over x), DIF, store transposed: Fc[b][i][y] holds kx=rev8(i)
__global__ __launch_bounds__(256) void k_fft1(const float* __restrict__ img, float2* __restrict__ Fc) {
  __shared__ float re[16 * PADS], im[16 * PADS];
  __shared__ float2 tw[128];
  int tid = threadIdx.x;
  int b = blockIdx.x >> 4;
  int y0 = (blockIdx.x & 15) << 4;
  tw_init(tw, tid);
  const float* src = img + (size_t)b * 65536 + (size_t)y0 * 256;
  for (int q = tid; q < 4096; q += 256) {
    int j = q >> 8, x = q & 255;
    re[j * PADS + x] = src[j * 256 + x];
    im[j * PADS + x] = 0.f;
  }
  fft_dif_fwd(re, im, tw, 16, tid);
  float2* dst = Fc + (size_t)b * 65536;
  for (int q = tid; q < 4096; q += 256) {
    int j = q & 15, i = q >> 4;
    dst[(size_t)i * 256 + y0 + j] = make_float2(re[j * PADS + i], im[j * PADS + i]);
  }
}

// F2: column FFT (over y) DIF fwd, * ctf_ext, DIT inverse; in-place on Fc rows
__global__ __launch_bounds__(256) void k_fft2(float2* __restrict__ Fc, const float* __restrict__ ctf) {
  __shared__ float re[4 * PADS], im[4 * PADS];
  __shared__ float2 tw[128];
  int tid = threadIdx.x;
  int b = blockIdx.x >> 6;
  int r0 = (blockIdx.x & 63) << 2;
  tw_init(tw, tid);
  float2* base = Fc + (size_t)b * 65536 + (size_t)r0 * 256;
  for (int q = tid; q < 1024; q += 256) {
    int p = q >> 8, y = q & 255;
    float2 v = base[p * 256 + y];
    re[p * PADS + y] = v.x; im[p * PADS + y] = v.y;
  }
  fft_dif_fwd(re, im, tw, 4, tid);
  for (int q = tid; q < 1024; q += 256) {
    int p = q >> 8, iy = q & 255;
    int kx = rev8(r0 + p), ky = rev8(iy);
    float c;
    if (kx <= 128) c = ctf[((size_t)b * 256 + ky) * 129 + kx];
    else           c = ctf[((size_t)b * 256 + ((256 - ky) & 255)) * 129 + (256 - kx)];
    re[p * PADS + iy] *= c; im[p * PADS + iy] *= c;
  }
  fft_dit_inv(re, im, tw, 4, tid);
  for (int q = tid; q < 1024; q += 256) {
    int p = q >> 8, y = q & 255;
    base[p * 256 + y] = make_float2(re[p * PADS + y], im[p * PADS + y]);
  }
}

// F3: inverse row FFT (over kx). Rows of Fc are already bitrev-ordered in kx -> DIT direct.
__global__ __launch_bounds__(256) void k_fft3(const float2* __restrict__ Fc, float* __restrict__ out) {
  __shared__ float re[16 * PADS], im[16 * PADS];
  __shared__ float2 tw[128];
  int tid = threadIdx.x;
  int b = blockIdx.x >> 4;
  int y0 = (blockIdx.x & 15) << 4;
  tw_init(tw, tid);
  const float2* src = Fc + (size_t)b * 65536;
  for (int q = tid; q < 4096; q += 256) {
    int j = q & 15, r = q >> 4;
    float2 v = src[(size_t)r * 256 + y0 + j];
    re[j * PADS + r] = v.x; im[j * PADS + r] = v.y;
  }
  fft_dit_inv(re, im, tw, 16, tid);
  float* dst = out + (size_t)b * 65536 + (size_t)y0 * 256;
  for (int q = tid; q < 4096; q += 256) {
    int j = q >> 8, x = q & 255;
    dst[j * 256 + x] = re[j * PADS + x] * (1.f / 65536.f);
  }
}

extern "C" void kernel_launch(void* const* d_in, const int* in_sizes, int n_in,
                              void* d_out, int out_size, void* d_ws, size_t ws_size,
                              hipStream_t stream) {
  const float* rows   = (const float*)d_in[0];
  const float* shifts = (const float*)d_in[1];
  const float* coords = (const float*)d_in[2];
  const float* W1     = (const float*)d_in[3];
  const float* b1     = (const float*)d_in[4];
  const float* Wh     = (const float*)d_in[5];
  const float* bh     = (const float*)d_in[6];
  const float* W5     = (const float*)d_in[7];
  const float* b5     = (const float*)d_in[8];
  const float* ctf    = (const float*)d_in[9];
  float* out = (float*)d_out;
  char* ws = (char*)d_ws;

  float*  partial = (float*)(ws + OFF_PART);
  float*  hbuf    = (float*)(ws + OFF_H);
  float*  Rbuf    = (float*)(ws + OFF_R);
  float*  img     = (float*)(ws + OFF_IMG);
  float*  tmp     = (float*)(ws + OFF_TMP);
  float2* Fc      = (float2*)(ws + OFF_FC);

  hipMemsetAsync(img, 0, (size_t)IMG_ELEMS * 4, stream);
  k_reduceT<<<256, 256, 0, stream>>>(coords, W1, partial);
  k_batch<<<1, 128, 0, stream>>>(partial, rows, b1, Wh, bh, hbuf, Rbuf);
  k_scatter<<<(N_ + 255) / 256, 256, 0, stream>>>(coords, W5, b5, hbuf, Rbuf, shifts, img);
  k_blurV<<<IMG_ELEMS / 256, 256, 0, stream>>>(img, tmp);
  k_blurH<<<IMG_ELEMS / 256, 256, 0, stream>>>(tmp, img);
  k_fft1<<<B_ * 16, 256, 0, stream>>>(img, Fc);
  k_fft2<<<B_ * 64, 256, 0, stream>>>(Fc, ctf);
  k_fft3<<<B_ * 16, 256, 0, stream>>>(Fc, out);
}

// Round 4
// 462.840 us; speedup vs baseline: 2.9841x; 2.9841x over previous
//
#include <hip/hip_runtime.h>
#include <math.h>

constexpr int B_  = 32;
constexpr int N_  = 200000;
constexpr int XSZ = 256;
constexpr int PADS = 257;                   // SoA LDS row stride (floats)

// scatter binning config
constexpr int NQ = 4;                        // quarters (image groups)
constexpr int BQ = 8;                        // images per quarter
constexpr int NSLAB = 64;                    // 4-row slabs per image
constexpr int BINS_Q = BQ * NSLAB;           // 512 bins per quarter
constexpr int FILL_BLOCKS = 64;
constexpr int PTS_PER_BLK = N_ / FILL_BLOCKS;     // 3125 (exact)
constexpr int SLICE_CAP = PTS_PER_BLK * BQ;       // 25000 entries per slice

// workspace layout (bytes) — total 33,631,232 (within round-2-proven footprint)
constexpr size_t OFF_PART = 0;                                    // 256*72*4
constexpr size_t OFF_H    = 73728;                                // 32*8*4
constexpr size_t OFF_R    = 74752;                                // 32*9*4
constexpr size_t OFF_IMG  = 76800;                                // 8 MB
constexpr size_t OFF_ENT  = OFF_IMG + (size_t)B_ * XSZ * XSZ * 4; // overlay region start
constexpr size_t ENT_N    = (size_t)FILL_BLOCKS * SLICE_CAP;      // 1,600,000
constexpr size_t OFF_DELB = OFF_ENT + ENT_N * 8;                  // +12.8MB
constexpr size_t OFF_IDX  = OFF_DELB + ENT_N * 4;                 // +19.2MB
constexpr size_t OFF_APR  = OFF_IDX + (size_t)FILL_BLOCKS * BINS_Q * 4;
// blur/FFT reuse the entries region after scatter is done:
constexpr size_t OFF_TMP  = OFF_ENT;                              // 8 MB
constexpr size_t OFF_FC   = OFF_ENT + (size_t)B_ * XSZ * XSZ * 4; // 16.77 MB (float2)

__device__ __forceinline__ int rev8(int x) { return (int)(__brev((unsigned)x) >> 24); }

// ---------------- T reduction: T[j,i,k] = sum_n coords[n,j] * W1[3n+i,k] ----------------
__global__ __launch_bounds__(256) void k_reduceT(const float* __restrict__ coords,
                                                 const float* __restrict__ W1,
                                                 float* __restrict__ partial) {
  float acc[72];
  #pragma unroll
  for (int t = 0; t < 72; ++t) acc[t] = 0.f;
  int idx = blockIdx.x * 256 + threadIdx.x;
  for (int n = idx; n < N_; n += 256 * 256) {
    float c0 = coords[n * 3 + 0], c1 = coords[n * 3 + 1], c2 = coords[n * 3 + 2];
    const float4* w4 = reinterpret_cast<const float4*>(W1 + (size_t)n * 24);
    #pragma unroll
    for (int i = 0; i < 3; ++i) {
      float4 wa = w4[i * 2 + 0], wb = w4[i * 2 + 1];
      float wv[8] = {wa.x, wa.y, wa.z, wa.w, wb.x, wb.y, wb.z, wb.w};
      #pragma unroll
      for (int k = 0; k < 8; ++k) {
        acc[i * 8 + k]      += c0 * wv[k];
        acc[24 + i * 8 + k] += c1 * wv[k];
        acc[48 + i * 8 + k] += c2 * wv[k];
      }
    }
  }
  #pragma unroll
  for (int t = 0; t < 72; ++t) {
    float v = acc[t];
    for (int off = 32; off > 0; off >>= 1) v += __shfl_down(v, off, 64);
    acc[t] = v;
  }
  __shared__ float sred[4][72];
  int lane = threadIdx.x & 63, wv_ = threadIdx.x >> 6;
  if (lane == 0) {
    #pragma unroll
    for (int t = 0; t < 72; ++t) sred[wv_][t] = acc[t];
  }
  __syncthreads();
  if (threadIdx.x < 72) {
    int t = threadIdx.x;
    partial[blockIdx.x * 72 + t] = sred[0][t] + sred[1][t] + sred[2][t] + sred[3][t];
  }
}

// ---------------- per-batch: finalize T, rotation matrices, MLP head ----------------
__global__ __launch_bounds__(128) void k_batch(const float* __restrict__ partial,
                                               const float* __restrict__ rows,
                                               const float* __restrict__ b1,
                                               const float* __restrict__ Wh,
                                               const float* __restrict__ bh,
                                               float* __restrict__ hbuf,
                                               float* __restrict__ Rbuf) {
  __shared__ float T[72];
  int tid = threadIdx.x;
  if (tid < 72) {
    double s = 0.0;
    for (int i = 0; i < 256; ++i) s += (double)partial[i * 72 + tid];
    T[tid] = (float)s;
  }
  __syncthreads();
  if (tid < B_) {
    int b = tid;
    float al = rows[b * 3 + 0], be = rows[b * 3 + 1], ga = rows[b * 3 + 2];
    float sa, ca, sb, cb, sg, cg;
    sincosf(al, &sa, &ca); sincosf(be, &sb, &cb); sincosf(ga, &sg, &cg);
    float R[3][3];
    R[0][0] = ca * cb * cg - sa * sg; R[0][1] = -ca * cb * sg - sa * cg; R[0][2] = ca * sb;
    R[1][0] = sa * cb * cg + ca * sg; R[1][1] = -sa * cb * sg + ca * cg; R[1][2] = sa * sb;
    R[2][0] = -sb * cg;               R[2][1] = sb * sg;                 R[2][2] = cb;
    float h[8];
    #pragma unroll
    for (int k = 0; k < 8; ++k) {
      float z = b1[k];
      #pragma unroll
      for (int i = 0; i < 3; ++i)
        #pragma unroll
        for (int j = 0; j < 3; ++j)
          z += R[i][j] * T[(j * 3 + i) * 8 + k];
      h[k] = sinf(30.f * z);
    }
    for (int l = 0; l < 3; ++l) {
      float nh[8];
      #pragma unroll
      for (int k2 = 0; k2 < 8; ++k2) {
        float z = bh[l * 8 + k2];
        #pragma unroll
        for (int k1 = 0; k1 < 8; ++k1) z += h[k1] * Wh[l * 64 + k1 * 8 + k2];
        nh[k2] = sinf(z);
      }
      #pragma unroll
      for (int k = 0; k < 8; ++k) h[k] = nh[k];
    }
    #pragma unroll
    for (int k = 0; k < 8; ++k) hbuf[b * 8 + k] = h[k];
    #pragma unroll
    for (int i = 0; i < 3; ++i)
      #pragma unroll
      for (int j = 0; j < 3; ++j) Rbuf[b * 9 + i * 3 + j] = R[i][j];
  }
}

// ---------------- pass 1: bin entries (px,py,delta) grouped by (image,slab) per slice ----------------
__global__ __launch_bounds__(512) void k_fill(const float* __restrict__ coords,
                                              const float* __restrict__ W5,
                                              const float* __restrict__ b5,
                                              const float* __restrict__ hbuf,
                                              const float* __restrict__ Rbuf,
                                              const float* __restrict__ shifts,
                                              float2* __restrict__ posb,
                                              float* __restrict__ delb,
                                              unsigned* __restrict__ idxt,
                                              int q) {
  __shared__ float sR[BQ][6];
  __shared__ float ss[BQ][2];
  __shared__ float sh[BQ][8];
  __shared__ unsigned hist[BINS_Q];
  __shared__ unsigned sbase[BINS_Q];
  __shared__ unsigned scur[BINS_Q];
  __shared__ unsigned wsum[8];
  int tid = threadIdx.x;
  if (tid < BQ) {
    int b = q * BQ + tid;
    #pragma unroll
    for (int j = 0; j < 3; ++j) { sR[tid][j] = Rbuf[b * 9 + j]; sR[tid][3 + j] = Rbuf[b * 9 + 3 + j]; }
    ss[tid][0] = shifts[b * 2]; ss[tid][1] = shifts[b * 2 + 1];
    #pragma unroll
    for (int k = 0; k < 8; ++k) sh[tid][k] = hbuf[b * 8 + k];
  }
  hist[tid] = 0;   // blockDim == BINS_Q == 512
  __syncthreads();
  int pbase = blockIdx.x * PTS_PER_BLK;
  // phase 1: count bins
  for (int k = 0; k < 7; ++k) {
    int off = tid + (k << 9);
    if (off < PTS_PER_BLK) {
      int p = pbase + off;
      float c0 = coords[p * 3], c1 = coords[p * 3 + 1], c2 = coords[p * 3 + 2];
      #pragma unroll
      for (int b = 0; b < BQ; ++b) {
        float px = (sR[b][0] * c0 + sR[b][1] * c1 + sR[b][2] * c2) * 100.f + 128.f - ss[b][0];
        float py = (sR[b][3] * c0 + sR[b][4] * c1 + sR[b][5] * c2) * 100.f + 128.f - ss[b][1];
        if (px >= -1.f && px < 256.f && py >= -1.f && py < 256.f) {
          int y0 = (int)floorf(py);
          int slab = (y0 < 0 ? 0 : y0) >> 2;
          atomicAdd(&hist[b * NSLAB + slab], 1u);
        }
      }
    }
  }
  __syncthreads();
  // phase 2: block-wide exclusive scan over 512 bins
  {
    unsigned orig = hist[tid];
    unsigned v = orig;
    int lane = tid & 63, wid = tid >> 6;
    #pragma unroll
    for (int d = 1; d < 64; d <<= 1) { unsigned u = __shfl_up(v, d, 64); if (lane >= d) v += u; }
    if (lane == 63) wsum[wid] = v;
    __syncthreads();
    unsigned woff = 0;
    #pragma unroll
    for (int w = 0; w < 8; ++w) if (w < wid) woff += wsum[w];
    unsigned excl = woff + v - orig;
    sbase[tid] = excl;
    scur[tid] = excl;
  }
  __syncthreads();
  // phase 3: recompute, reserve slot via LDS cursor, write entry
  size_t slice0 = (size_t)blockIdx.x * SLICE_CAP;
  for (int k = 0; k < 7; ++k) {
    int off = tid + (k << 9);
    if (off < PTS_PER_BLK) {
      int p = pbase + off;
      float c0 = coords[p * 3], c1 = coords[p * 3 + 1], c2 = coords[p * 3 + 2];
      float b5n = b5[p];
      float w5v[8];
      #pragma unroll
      for (int kk = 0; kk < 8; ++kk) w5v[kk] = W5[(size_t)kk * N_ + p];
      #pragma unroll
      for (int b = 0; b < BQ; ++b) {
        float px = (sR[b][0] * c0 + sR[b][1] * c1 + sR[b][2] * c2) * 100.f + 128.f - ss[b][0];
        float py = (sR[b][3] * c0 + sR[b][4] * c1 + sR[b][5] * c2) * 100.f + 128.f - ss[b][1];
        if (px >= -1.f && px < 256.f && py >= -1.f && py < 256.f) {
          int y0 = (int)floorf(py);
          int slab = (y0 < 0 ? 0 : y0) >> 2;
          int bin = b * NSLAB + slab;
          unsigned r = atomicAdd(&scur[bin], 1u);
          if (r < (unsigned)SLICE_CAP) {
            float delta = b5n;
            #pragma unroll
            for (int kk = 0; kk < 8; ++kk) delta += sh[b][kk] * w5v[kk];
            posb[slice0 + r] = make_float2(px, py);
            delb[slice0 + r] = delta;
          }
        }
      }
    }
  }
  __syncthreads();
  // idx table: pack (cnt<<16)|base
  {
    unsigned base = sbase[tid], cnt = scur[tid] - base;
    idxt[blockIdx.x * BINS_Q + tid] = (cnt << 16) | base;
  }
}

// ---------------- pass 2: accumulate bin entries into LDS slab tile, plain-store rows ----------------
__global__ __launch_bounds__(256) void k_scatter2(const float2* __restrict__ posb,
                                                  const float* __restrict__ delb,
                                                  const unsigned* __restrict__ idxt,
                                                  float* __restrict__ img,
                                                  float* __restrict__ apron,
                                                  int q) {
  __shared__ float tile[5 * XSZ];
  __shared__ unsigned sidx[FILL_BLOCKS];
  int tid = threadIdx.x;
  int bin = blockIdx.x;                 // [0, 512)
  int b_local = bin >> 6;               // / NSLAB
  int s = bin & 63;
  for (int i = tid; i < 5 * XSZ; i += 256) tile[i] = 0.f;
  if (tid < FILL_BLOCKS) sidx[tid] = idxt[tid * BINS_Q + bin];
  __syncthreads();
  int wid = tid >> 6, lane = tid & 63;
  int ybase = s << 2;
  for (int s2 = wid; s2 < FILL_BLOCKS; s2 += 4) {
    unsigned pc = sidx[s2];
    int cnt = (int)(pc >> 16);
    int base = (int)(pc & 0xFFFFu);
    size_t sb = (size_t)s2 * SLICE_CAP + base;
    for (int i = lane; i < cnt; i += 64) {
      float2 pp = posb[sb + i];
      float delta = delb[sb + i];
      float x0f = floorf(pp.x), y0f = floorf(pp.y);
      float fx = pp.x - x0f, fy = pp.y - y0f;
      int x0 = (int)x0f;
      int r0 = (int)y0f - ybase;        // in [-1,3]
      float wy0 = (1.f - fy) * delta, wy1 = fy * delta;
      bool xl = (x0 >= 0), xr = (x0 <= 254);
      if (r0 >= 0) {
        int c0i = r0 * XSZ + x0;
        if (xl) atomicAdd(&tile[c0i], (1.f - fx) * wy0);
        if (xr) atomicAdd(&tile[c0i + 1], fx * wy0);
      }
      int c1i = (r0 + 1) * XSZ + x0;
      if (xl) atomicAdd(&tile[c1i], (1.f - fx) * wy1);
      if (xr) atomicAdd(&tile[c1i + 1], fx * wy1);
    }
  }
  __syncthreads();
  int b_global = q * BQ + b_local;
  float* imbase = img + (size_t)b_global * 65536 + (size_t)ybase * XSZ;
  for (int i = tid; i < 4 * XSZ; i += 256) imbase[i] = tile[i];
  apron[(size_t)(q * BINS_Q + bin) * XSZ + tid] = tile[4 * XSZ + tid];
}

// ---------------- apron fixup: add boundary rows ----------------
__global__ __launch_bounds__(256) void k_apron(const float* __restrict__ apron,
                                               float* __restrict__ img) {
  int bid = blockIdx.x;                 // b_global*64 + s
  int s = bid & 63;
  if (s == 63) return;                  // row 256 discarded
  int b = bid >> 6;
  int row = (s + 1) << 2;
  float* dst = img + (size_t)b * 65536 + (size_t)row * XSZ;
  dst[threadIdx.x] += apron[(size_t)bid * XSZ + threadIdx.x];
}

// ---------------- separable Gaussian blur (zero-padded SAME) ----------------
__device__ __forceinline__ float bwv(int i) {
  const float bw[7] = {0.004433048f, 0.054005582f, 0.242036226f, 0.399050280f,
                       0.242036226f, 0.054005582f, 0.004433048f};
  return bw[i];
}

__global__ __launch_bounds__(256) void k_blurV(const float* __restrict__ in, float* __restrict__ out) {
  int i = blockIdx.x * 256 + threadIdx.x;
  int x = i & 255;
  int y = (i >> 8) & 255;
  const float* p = in + (i & ~65535);
  float s = 0.f;
  #pragma unroll
  for (int d = -3; d <= 3; ++d) {
    int yy = y + d;
    if ((unsigned)yy < XSZ) s += bwv(d + 3) * p[(yy << 8) + x];
  }
  out[i] = s;
}

__global__ __launch_bounds__(256) void k_blurH(const float* __restrict__ in, float* __restrict__ out) {
  int i = blockIdx.x * 256 + threadIdx.x;
  int x = i & 255;
  float s = 0.f;
  #pragma unroll
  for (int d = -3; d <= 3; ++d) {
    int xx = x + d;
    if ((unsigned)xx < XSZ) s += bwv(d + 3) * in[i + d];
  }
  out[i] = s;
}

// ---------------- FFT helpers: 256-pt, SoA in LDS, stride PADS ----------------
__device__ __forceinline__ void fft_dif_fwd(float* re, float* im, const float2* tw, int P, int tid) {
  for (int s = 7; s >= 0; --s) {
    __syncthreads();
    int half = 1 << s;
    for (int q = tid; q < (P << 7); q += 256) {
      int p = q >> 7, k = q & 127;
      int j = k & (half - 1);
      int i0 = ((k >> s) << (s + 1)) | j;
      int i1 = i0 + half;
      float* rp = re + p * PADS; float* ip = im + p * PADS;
      float ar = rp[i0], ai = ip[i0], br = rp[i1], bi = ip[i1];
      rp[i0] = ar + br; ip[i0] = ai + bi;
      float tr = ar - br, ti = ai - bi;
      float2 w = tw[j << (7 - s)];
      rp[i1] = tr * w.x - ti * w.y;
      ip[i1] = tr * w.y + ti * w.x;
    }
  }
  __syncthreads();
}

__device__ __forceinline__ void fft_dit_inv(float* re, float* im, const float2* tw, int P, int tid) {
  for (int s = 0; s <= 7; ++s) {
    __syncthreads();
    int half = 1 << s;
    for (int q = tid; q < (P << 7); q += 256) {
      int p = q >> 7, k = q & 127;
      int j = k & (half - 1);
      int i0 = ((k >> s) << (s + 1)) | j;
      int i1 = i0 + half;
      float* rp = re + p * PADS; float* ip = im + p * PADS;
      float2 w = tw[j << (7 - s)];               // conj -> (w.x, -w.y)
      float br = rp[i1], bi = ip[i1];
      float tr = br * w.x + bi * w.y;
      float ti = bi * w.x - br * w.y;
      float ar = rp[i0], ai = ip[i0];
      rp[i0] = ar + tr; ip[i0] = ai + ti;
      rp[i1] = ar - tr; ip[i1] = ai - ti;
    }
  }
  __syncthreads();
}

__device__ __forceinline__ void tw_init(float2* tw, int tid) {
  for (int k = tid; k < 128; k += 256) {
    float s_, c_;
    sincosf(-6.2831853071795864769f * (float)k / 256.0f, &s_, &c_);
    tw[k] = make_float2(c_, s_);
  }
}

// F1: row FFT (over x), DIF, store transposed: Fc[b][i][y] holds kx=rev8(i)
__global__ __launch_bounds__(256) void k_fft1(const float* __restrict__ img, float2* __restrict__ Fc) {
  __shared__ float re[16 * PADS], im[16 * PADS];
  __shared__ float2 tw[128];
  int tid = threadIdx.x;
  int b = blockIdx.x >> 4;
  int y0 = (blockIdx.x & 15) << 4;
  tw_init(tw, tid);
  const float* src = img + (size_t)b * 65536 + (size_t)y0 * 256;
  for (int q = tid; q < 4096; q += 256) {
    int j = q >> 8, x = q & 255;
    re[j * PADS + x] = src[j * 256 + x];
    im[j * PADS + x] = 0.f;
  }
  fft_dif_fwd(re, im, tw, 16, tid);
  float2* dst = Fc + (size_t)b * 65536;
  for (int q = tid; q < 4096; q += 256) {
    int j = q & 15, i = q >> 4;
    dst[(size_t)i * 256 + y0 + j] = make_float2(re[j * PADS + i], im[j * PADS + i]);
  }
}

// F2: column FFT (over y) DIF fwd, * ctf_ext, DIT inverse; in-place on Fc rows
__global__ __launch_bounds__(256) void k_fft2(float2* __restrict__ Fc, const float* __restrict__ ctf) {
  __shared__ float re[4 * PADS], im[4 * PADS];
  __shared__ float2 tw[128];
  int tid = threadIdx.x;
  int b = blockIdx.x >> 6;
  int r0 = (blockIdx.x & 63) << 2;
  tw_init(tw, tid);
  float2* base = Fc + (size_t)b * 65536 + (size_t)r0 * 256;
  for (int q = tid; q < 1024; q += 256) {
    int p = q >> 8, y = q & 255;
    float2 v = base[p * 256 + y];
    re[p * PADS + y] = v.x; im[p * PADS + y] = v.y;
  }
  fft_dif_fwd(re, im, tw, 4, tid);
  for (int q = tid; q < 1024; q += 256) {
    int p = q >> 8, iy = q & 255;
    int kx = rev8(r0 + p), ky = rev8(iy);
    float c;
    if (kx <= 128) c = ctf[((size_t)b * 256 + ky) * 129 + kx];
    else           c = ctf[((size_t)b * 256 + ((256 - ky) & 255)) * 129 + (256 - kx)];
    re[p * PADS + iy] *= c; im[p * PADS + iy] *= c;
  }
  fft_dit_inv(re, im, tw, 4, tid);
  for (int q = tid; q < 1024; q += 256) {
    int p = q >> 8, y = q & 255;
    base[p * 256 + y] = make_float2(re[p * PADS + y], im[p * PADS + y]);
  }
}

// F3: inverse row FFT (over kx). Rows of Fc are already bitrev-ordered in kx -> DIT direct.
__global__ __launch_bounds__(256) void k_fft3(const float2* __restrict__ Fc, float* __restrict__ out) {
  __shared__ float re[16 * PADS], im[16 * PADS];
  __shared__ float2 tw[128];
  int tid = threadIdx.x;
  int b = blockIdx.x >> 4;
  int y0 = (blockIdx.x & 15) << 4;
  tw_init(tw, tid);
  const float2* src = Fc + (size_t)b * 65536;
  for (int q = tid; q < 4096; q += 256) {
    int j = q & 15, r = q >> 4;
    float2 v = src[(size_t)r * 256 + y0 + j];
    re[j * PADS + r] = v.x; im[j * PADS + r] = v.y;
  }
  fft_dit_inv(re, im, tw, 16, tid);
  float* dst = out + (size_t)b * 65536 + (size_t)y0 * 256;
  for (int q = tid; q < 4096; q += 256) {
    int j = q >> 8, x = q & 255;
    dst[j * 256 + x] = re[j * PADS + x] * (1.f / 65536.f);
  }
}

extern "C" void kernel_launch(void* const* d_in, const int* in_sizes, int n_in,
                              void* d_out, int out_size, void* d_ws, size_t ws_size,
                              hipStream_t stream) {
  const float* rows   = (const float*)d_in[0];
  const float* shifts = (const float*)d_in[1];
  const float* coords = (const float*)d_in[2];
  const float* W1     = (const float*)d_in[3];
  const float* b1     = (const float*)d_in[4];
  const float* Wh     = (const float*)d_in[5];
  const float* bh     = (const float*)d_in[6];
  const float* W5     = (const float*)d_in[7];
  const float* b5     = (const float*)d_in[8];
  const float* ctf    = (const float*)d_in[9];
  float* out = (float*)d_out;
  char* ws = (char*)d_ws;

  float*    partial = (float*)(ws + OFF_PART);
  float*    hbuf    = (float*)(ws + OFF_H);
  float*    Rbuf    = (float*)(ws + OFF_R);
  float*    img     = (float*)(ws + OFF_IMG);
  float2*   posb    = (float2*)(ws + OFF_ENT);
  float*    delb    = (float*)(ws + OFF_DELB);
  unsigned* idxt    = (unsigned*)(ws + OFF_IDX);
  float*    apron   = (float*)(ws + OFF_APR);
  float*    tmp     = (float*)(ws + OFF_TMP);
  float2*   Fc      = (float2*)(ws + OFF_FC);

  k_reduceT<<<256, 256, 0, stream>>>(coords, W1, partial);
  k_batch<<<1, 128, 0, stream>>>(partial, rows, b1, Wh, bh, hbuf, Rbuf);
  for (int q = 0; q < NQ; ++q) {
    k_fill<<<FILL_BLOCKS, 512, 0, stream>>>(coords, W5, b5, hbuf, Rbuf, shifts, posb, delb, idxt, q);
    k_scatter2<<<BINS_Q, 256, 0, stream>>>(posb, delb, idxt, img, apron, q);
  }
  k_apron<<<B_ * NSLAB, 256, 0, stream>>>(apron, img);
  k_blurV<<<B_ * XSZ * XSZ / 256, 256, 0, stream>>>(img, tmp);
  k_blurH<<<B_ * XSZ * XSZ / 256, 256, 0, stream>>>(tmp, img);
  k_fft1<<<B_ * 16, 256, 0, stream>>>(img, Fc);
  k_fft2<<<B_ * 64, 256, 0, stream>>>(Fc, ctf);
  k_fft3<<<B_ * 16, 256, 0, stream>>>(Fc, out);
}

// Round 6
// 322.425 us; speedup vs baseline: 4.2837x; 1.4355x over previous
//
#include <hip/hip_runtime.h>
#include <math.h>

constexpr int B_  = 32;
constexpr int N_  = 200000;
constexpr int XSZ = 256;
constexpr int PADS = 257;                   // SoA LDS row stride (floats)

// workspace layout (bytes) — total ~33.4 MB (within round-4-proven footprint)
constexpr size_t OFF_PART = 0;                                    // 256*72*4
constexpr size_t OFF_H    = 73728;                                // 32*8*4
constexpr size_t OFF_R    = 74752;                                // 32*9*4
constexpr size_t OFF_IMG  = 76800;                                // 8 MB
constexpr size_t OFF_TMP  = OFF_IMG + (size_t)B_ * XSZ * XSZ * 4; // 8 MB (blur tmp)
constexpr size_t OFF_W5T  = OFF_TMP;                              // 6.4 MB, dead before blur
constexpr size_t OFF_FC   = OFF_TMP + (size_t)B_ * XSZ * XSZ * 4; // 16.8 MB (float2)

__device__ __forceinline__ int rev8(int x) { return (int)(__brev((unsigned)x) >> 24); }

// ---------------- T reduction: T[j,i,k] = sum_n coords[n,j] * W1[3n+i,k] ----------------
__global__ __launch_bounds__(256) void k_reduceT(const float* __restrict__ coords,
                                                 const float* __restrict__ W1,
                                                 float* __restrict__ partial) {
  float acc[72];
  #pragma unroll
  for (int t = 0; t < 72; ++t) acc[t] = 0.f;
  int idx = blockIdx.x * 256 + threadIdx.x;
  for (int n = idx; n < N_; n += 256 * 256) {
    float c0 = coords[n * 3 + 0], c1 = coords[n * 3 + 1], c2 = coords[n * 3 + 2];
    const float4* w4 = reinterpret_cast<const float4*>(W1 + (size_t)n * 24);
    #pragma unroll
    for (int i = 0; i < 3; ++i) {
      float4 wa = w4[i * 2 + 0], wb = w4[i * 2 + 1];
      float wv[8] = {wa.x, wa.y, wa.z, wa.w, wb.x, wb.y, wb.z, wb.w};
      #pragma unroll
      for (int k = 0; k < 8; ++k) {
        acc[i * 8 + k]      += c0 * wv[k];
        acc[24 + i * 8 + k] += c1 * wv[k];
        acc[48 + i * 8 + k] += c2 * wv[k];
      }
    }
  }
  #pragma unroll
  for (int t = 0; t < 72; ++t) {
    float v = acc[t];
    for (int off = 32; off > 0; off >>= 1) v += __shfl_down(v, off, 64);
    acc[t] = v;
  }
  __shared__ float sred[4][72];
  int lane = threadIdx.x & 63, wv_ = threadIdx.x >> 6;
  if (lane == 0) {
    #pragma unroll
    for (int t = 0; t < 72; ++t) sred[wv_][t] = acc[t];
  }
  __syncthreads();
  if (threadIdx.x < 72) {
    int t = threadIdx.x;
    partial[blockIdx.x * 72 + t] = sred[0][t] + sred[1][t] + sred[2][t] + sred[3][t];
  }
}

// ---------------- per-batch: finalize T, rotation matrices, MLP head ----------------
__global__ __launch_bounds__(128) void k_batch(const float* __restrict__ partial,
                                               const float* __restrict__ rows,
                                               const float* __restrict__ b1,
                                               const float* __restrict__ Wh,
                                               const float* __restrict__ bh,
                                               float* __restrict__ hbuf,
                                               float* __restrict__ Rbuf) {
  __shared__ float T[72];
  int tid = threadIdx.x;
  if (tid < 72) {
    double s = 0.0;
    for (int i = 0; i < 256; ++i) s += (double)partial[i * 72 + tid];
    T[tid] = (float)s;
  }
  __syncthreads();
  if (tid < B_) {
    int b = tid;
    float al = rows[b * 3 + 0], be = rows[b * 3 + 1], ga = rows[b * 3 + 2];
    float sa, ca, sb, cb, sg, cg;
    sincosf(al, &sa, &ca); sincosf(be, &sb, &cb); sincosf(ga, &sg, &cg);
    float R[3][3];
    R[0][0] = ca * cb * cg - sa * sg; R[0][1] = -ca * cb * sg - sa * cg; R[0][2] = ca * sb;
    R[1][0] = sa * cb * cg + ca * sg; R[1][1] = -sa * cb * sg + ca * cg; R[1][2] = sa * sb;
    R[2][0] = -sb * cg;               R[2][1] = sb * sg;                 R[2][2] = cb;
    float h[8];
    #pragma unroll
    for (int k = 0; k < 8; ++k) {
      float z = b1[k];
      #pragma unroll
      for (int i = 0; i < 3; ++i)
        #pragma unroll
        for (int j = 0; j < 3; ++j)
          z += R[i][j] * T[(j * 3 + i) * 8 + k];
      h[k] = sinf(30.f * z);
    }
    for (int l = 0; l < 3; ++l) {
      float nh[8];
      #pragma unroll
      for (int k2 = 0; k2 < 8; ++k2) {
        float z = bh[l * 8 + k2];
        #pragma unroll
        for (int k1 = 0; k1 < 8; ++k1) z += h[k1] * Wh[l * 64 + k1 * 8 + k2];
        nh[k2] = sinf(z);
      }
      #pragma unroll
      for (int k = 0; k < 8; ++k) h[k] = nh[k];
    }
    #pragma unroll
    for (int k = 0; k < 8; ++k) hbuf[b * 8 + k] = h[k];
    #pragma unroll
    for (int i = 0; i < 3; ++i)
      #pragma unroll
      for (int j = 0; j < 3; ++j) Rbuf[b * 9 + i * 3 + j] = R[i][j];
  }
}

// ---------------- W5 transpose: W5T[n][k] = W5[k][n] (coalesced delta loads later) ----------------
__global__ __launch_bounds__(256) void k_w5t(const float* __restrict__ W5, float* __restrict__ w5t) {
  int n = blockIdx.x * 256 + threadIdx.x;
  if (n >= N_) return;
  float v[8];
  #pragma unroll
  for (int k = 0; k < 8; ++k) v[k] = W5[(size_t)k * N_ + n];
  float4* dst = reinterpret_cast<float4*>(w5t + (size_t)n * 8);
  dst[0] = make_float4(v[0], v[1], v[2], v[3]);
  dst[1] = make_float4(v[4], v[5], v[6], v[7]);
}

// ---------------- direct scatter: block = (image, 32-row band); LDS tile accumulate ----------------
__global__ __launch_bounds__(1024) void k_direct(const float* __restrict__ coords,
                                                 const float* __restrict__ w5t,
                                                 const float* __restrict__ b5,
                                                 const float* __restrict__ hbuf,
                                                 const float* __restrict__ Rbuf,
                                                 const float* __restrict__ shifts,
                                                 float* __restrict__ img) {
  __shared__ float tile[32 * XSZ];     // 32 KB
  __shared__ float sp[16];             // A0..A5 (100*R rows), bx, by, h0..h7
  int tid = threadIdx.x;
  int b = blockIdx.x >> 3;
  int band = blockIdx.x & 7;
  int r0 = band << 5;
  if (tid < 6)       sp[tid] = Rbuf[b * 9 + tid] * 100.f;
  else if (tid < 8)  sp[tid] = 128.f - shifts[b * 2 + (tid - 6)];
  else if (tid < 16) sp[tid] = hbuf[b * 8 + (tid - 8)];
  for (int i = tid; i < 32 * XSZ; i += 1024) tile[i] = 0.f;
  __syncthreads();
  float A0 = sp[0], A1 = sp[1], A2 = sp[2];
  float A3 = sp[3], A4 = sp[4], A5 = sp[5];
  float bx = sp[6], by = sp[7];
  float h0 = sp[8], h1 = sp[9], h2 = sp[10], h3 = sp[11];
  float h4 = sp[12], h5 = sp[13], h6 = sp[14], h7 = sp[15];
  float ylo = (float)(r0 - 1), yhi = (float)(r0 + 32);
  for (int n = tid; n < N_; n += 1024) {
    float c0 = coords[n * 3], c1 = coords[n * 3 + 1], c2 = coords[n * 3 + 2];
    float px = fmaf(A0, c0, fmaf(A1, c1, fmaf(A2, c2, bx)));
    float py = fmaf(A3, c0, fmaf(A4, c1, fmaf(A5, c2, by)));
    if (py >= ylo && py < yhi && px >= -1.f && px < 256.f) {
      const float4* w = reinterpret_cast<const float4*>(w5t + (size_t)n * 8);
      float4 wa = w[0], wb = w[1];
      float delta = b5[n];
      delta = fmaf(h0, wa.x, delta); delta = fmaf(h1, wa.y, delta);
      delta = fmaf(h2, wa.z, delta); delta = fmaf(h3, wa.w, delta);
      delta = fmaf(h4, wb.x, delta); delta = fmaf(h5, wb.y, delta);
      delta = fmaf(h6, wb.z, delta); delta = fmaf(h7, wb.w, delta);
      float x0f = floorf(px), y0f = floorf(py);
      float fx = px - x0f, fy = py - y0f;
      int x0 = (int)x0f;
      int r = (int)y0f - r0;           // in [-1, 31]
      float wy0 = (1.f - fy) * delta, wy1 = fy * delta;
      bool xl = (x0 >= 0), xr = (x0 <= 254);
      if (r >= 0) {                    // row y0 owned by this band
        int c0i = r * XSZ + x0;
        if (xl) atomicAdd(&tile[c0i], (1.f - fx) * wy0);
        if (xr) atomicAdd(&tile[c0i + 1], fx * wy0);
      }
      if (r < 31) {                    // row y0+1 owned by this band
        int c1i = (r + 1) * XSZ + x0;
        if (xl) atomicAdd(&tile[c1i], (1.f - fx) * wy1);
        if (xr) atomicAdd(&tile[c1i + 1], fx * wy1);
      }
    }
  }
  __syncthreads();
  float* dst = img + (size_t)b * 65536 + (size_t)r0 * XSZ;
  for (int i = tid; i < 32 * XSZ; i += 1024) dst[i] = tile[i];
}

// ---------------- separable Gaussian blur (zero-padded SAME) ----------------
__device__ __forceinline__ float bwv(int i) {
  const float bw[7] = {0.004433048f, 0.054005582f, 0.242036226f, 0.399050280f,
                       0.242036226f, 0.054005582f, 0.004433048f};
  return bw[i];
}

__global__ __launch_bounds__(256) void k_blurV(const float* __restrict__ in, float* __restrict__ out) {
  int i = blockIdx.x * 256 + threadIdx.x;
  int x = i & 255;
  int y = (i >> 8) & 255;
  const float* p = in + (i & ~65535);
  float s = 0.f;
  #pragma unroll
  for (int d = -3; d <= 3; ++d) {
    int yy = y + d;
    if ((unsigned)yy < XSZ) s += bwv(d + 3) * p[(yy << 8) + x];
  }
  out[i] = s;
}

__global__ __launch_bounds__(256) void k_blurH(const float* __restrict__ in, float* __restrict__ out) {
  int i = blockIdx.x * 256 + threadIdx.x;
  int x = i & 255;
  float s = 0.f;
  #pragma unroll
  for (int d = -3; d <= 3; ++d) {
    int xx = x + d;
    if ((unsigned)xx < XSZ) s += bwv(d + 3) * in[i + d];
  }
  out[i] = s;
}

// ---------------- FFT helpers: 256-pt, SoA in LDS, stride PADS ----------------
__device__ __forceinline__ void fft_dif_fwd(float* re, float* im, const float2* tw, int P, int tid) {
  for (int s = 7; s >= 0; --s) {
    __syncthreads();
    int half = 1 << s;
    for (int q = tid; q < (P << 7); q += 256) {
      int p = q >> 7, k = q & 127;
      int j = k & (half - 1);
      int i0 = ((k >> s) << (s + 1)) | j;
      int i1 = i0 + half;
      float* rp = re + p * PADS; float* ip = im + p * PADS;
      float ar = rp[i0], ai = ip[i0], br = rp[i1], bi = ip[i1];
      rp[i0] = ar + br; ip[i0] = ai + bi;
      float tr = ar - br, ti = ai - bi;
      float2 w = tw[j << (7 - s)];
      rp[i1] = tr * w.x - ti * w.y;
      ip[i1] = tr * w.y + ti * w.x;
    }
  }
  __syncthreads();
}

__device__ __forceinline__ void fft_dit_inv(float* re, float* im, const float2* tw, int P, int tid) {
  for (int s = 0; s <= 7; ++s) {
    __syncthreads();
    int half = 1 << s;
    for (int q = tid; q < (P << 7); q += 256) {
      int p = q >> 7, k = q & 127;
      int j = k & (half - 1);
      int i0 = ((k >> s) << (s + 1)) | j;
      int i1 = i0 + half;
      float* rp = re + p * PADS; float* ip = im + p * PADS;
      float2 w = tw[j << (7 - s)];               // conj -> (w.x, -w.y)
      float br = rp[i1], bi = ip[i1];
      float tr = br * w.x + bi * w.y;
      float ti = bi * w.x - br * w.y;
      float ar = rp[i0], ai = ip[i0];
      rp[i0] = ar + tr; ip[i0] = ai + ti;
      rp[i1] = ar - tr; ip[i1] = ai - ti;
    }
  }
  __syncthreads();
}

__device__ __forceinline__ void tw_init(float2* tw, int tid) {
  for (int k = tid; k < 128; k += 256) {
    float s_, c_;
    sincosf(-6.2831853071795864769f * (float)k / 256.0f, &s_, &c_);
    tw[k] = make_float2(c_, s_);
  }
}

// F1: row FFT (over x), DIF, store transposed: Fc[b][i][y] holds kx=rev8(i)
__global__ __launch_bounds__(256) void k_fft1(const float* __restrict__ img, float2* __restrict__ Fc) {
  __shared__ float re[16 * PADS], im[16 * PADS];
  __shared__ float2 tw[128];
  int tid = threadIdx.x;
  int b = blockIdx.x >> 4;
  int y0 = (blockIdx.x & 15) << 4;
  tw_init(tw, tid);
  const float* src = img + (size_t)b * 65536 + (size_t)y0 * 256;
  for (int q = tid; q < 4096; q += 256) {
    int j = q >> 8, x = q & 255;
    re[j * PADS + x] = src[j * 256 + x];
    im[j * PADS + x] = 0.f;
  }
  fft_dif_fwd(re, im, tw, 16, tid);
  float2* dst = Fc + (size_t)b * 65536;
  for (int q = tid; q < 4096; q += 256) {
    int j = q & 15, i = q >> 4;
    dst[(size_t)i * 256 + y0 + j] = make_float2(re[j * PADS + i], im[j * PADS + i]);
  }
}

// F2: column FFT (over y) DIF fwd, * ctf_ext, DIT inverse; in-place on Fc rows
__global__ __launch_bounds__(256) void k_fft2(float2* __restrict__ Fc, const float* __restrict__ ctf) {
  __shared__ float re[4 * PADS], im[4 * PADS];
  __shared__ float2 tw[128];
  int tid = threadIdx.x;
  int b = blockIdx.x >> 6;
  int r0 = (blockIdx.x & 63) << 2;
  tw_init(tw, tid);
  float2* base = Fc + (size_t)b * 65536 + (size_t)r0 * 256;
  for (int q = tid; q < 1024; q += 256) {
    int p = q >> 8, y = q & 255;
    float2 v = base[p * 256 + y];
    re[p * PADS + y] = v.x; im[p * PADS + y] = v.y;
  }
  fft_dif_fwd(re, im, tw, 4, tid);
  for (int q = tid; q < 1024; q += 256) {
    int p = q >> 8, iy = q & 255;
    int kx = rev8(r0 + p), ky = rev8(iy);
    float c;
    if (kx <= 128) c = ctf[((size_t)b * 256 + ky) * 129 + kx];
    else           c = ctf[((size_t)b * 256 + ((256 - ky) & 255)) * 129 + (256 - kx)];
    re[p * PADS + iy] *= c; im[p * PADS + iy] *= c;
  }
  fft_dit_inv(re, im, tw, 4, tid);
  for (int q = tid; q < 1024; q += 256) {
    int p = q >> 8, y = q & 255;
    base[p * 256 + y] = make_float2(re[p * PADS + y], im[p * PADS + y]);
  }
}

// F3: inverse row FFT (over kx). Rows of Fc are already bitrev-ordered in kx -> DIT direct.
__global__ __launch_bounds__(256) void k_fft3(const float2* __restrict__ Fc, float* __restrict__ out) {
  __shared__ float re[16 * PADS], im[16 * PADS];
  __shared__ float2 tw[128];
  int tid = threadIdx.x;
  int b = blockIdx.x >> 4;
  int y0 = (blockIdx.x & 15) << 4;
  tw_init(tw, tid);
  const float2* src = Fc + (size_t)b * 65536;
  for (int q = tid; q < 4096; q += 256) {
    int j = q & 15, r = q >> 4;
    float2 v = src[(size_t)r * 256 + y0 + j];
    re[j * PADS + r] = v.x; im[j * PADS + r] = v.y;
  }
  fft_dit_inv(re, im, tw, 16, tid);
  float* dst = out + (size_t)b * 65536 + (size_t)y0 * 256;
  for (int q = tid; q < 4096; q += 256) {
    int j = q >> 8, x = q & 255;
    dst[j * 256 + x] = re[j * PADS + x] * (1.f / 65536.f);
  }
}

extern "C" void kernel_launch(void* const* d_in, const int* in_sizes, int n_in,
                              void* d_out, int out_size, void* d_ws, size_t ws_size,
                              hipStream_t stream) {
  const float* rows   = (const float*)d_in[0];
  const float* shifts = (const float*)d_in[1];
  const float* coords = (const float*)d_in[2];
  const float* W1     = (const float*)d_in[3];
  const float* b1     = (const float*)d_in[4];
  const float* Wh     = (const float*)d_in[5];
  const float* bh     = (const float*)d_in[6];
  const float* W5     = (const float*)d_in[7];
  const float* b5     = (const float*)d_in[8];
  const float* ctf    = (const float*)d_in[9];
  float* out = (float*)d_out;
  char* ws = (char*)d_ws;

  float*    partial = (float*)(ws + OFF_PART);
  float*    hbuf    = (float*)(ws + OFF_H);
  float*    Rbuf    = (float*)(ws + OFF_R);
  float*    img     = (float*)(ws + OFF_IMG);
  float*    w5t     = (float*)(ws + OFF_W5T);
  float*    tmp     = (float*)(ws + OFF_TMP);
  float2*   Fc      = (float2*)(ws + OFF_FC);

  k_reduceT<<<256, 256, 0, stream>>>(coords, W1, partial);
  k_batch<<<1, 128, 0, stream>>>(partial, rows, b1, Wh, bh, hbuf, Rbuf);
  k_w5t<<<(N_ + 255) / 256, 256, 0, stream>>>(W5, w5t);
  k_direct<<<B_ * 8, 1024, 0, stream>>>(coords, w5t, b5, hbuf, Rbuf, shifts, img);
  k_blurV<<<B_ * XSZ * XSZ / 256, 256, 0, stream>>>(img, tmp);
  k_blurH<<<B_ * XSZ * XSZ / 256, 256, 0, stream>>>(tmp, img);
  k_fft1<<<B_ * 16, 256, 0, stream>>>(img, Fc);
  k_fft2<<<B_ * 64, 256, 0, stream>>>(Fc, ctf);
  k_fft3<<<B_ * 16, 256, 0, stream>>>(Fc, out);
}

// Round 8
// 315.584 us; speedup vs baseline: 4.3766x; 1.0217x over previous
//
#include <hip/hip_runtime.h>
#include <math.h>

constexpr int B_  = 32;
constexpr int N_  = 200000;
constexpr int XSZ = 256;
constexpr int PADS = 257;                   // SoA LDS row stride (floats)

// workspace layout (bytes) — total 33,631,232 (identical to proven footprint)
constexpr size_t OFF_PART  = 0;                                    // 256*72*4
constexpr size_t OFF_H     = 73728;                                // 32*8*4
constexpr size_t OFF_R     = 74752;                                // 32*9*4
constexpr size_t OFF_IMG   = 76800;                                // 8 MB
constexpr size_t OFF_TILES = OFF_IMG + (size_t)B_ * XSZ * XSZ * 4; // 16 MB (512 tiles)
constexpr size_t OFF_W5T   = OFF_TILES + (size_t)512 * 8192 * 4;   // 6.4 MB
// post-scatter overlays (tiles/w5t dead after k_merge):
constexpr size_t OFF_TMP   = OFF_TILES;                            // 8 MB blur tmp
constexpr size_t OFF_FC    = OFF_TILES + (size_t)B_ * XSZ * XSZ * 4; // 16.8 MB float2

__device__ __forceinline__ int rev8(int x) { return (int)(__brev((unsigned)x) >> 24); }

// ---------------- T reduction: T[j,i,k] = sum_n coords[n,j] * W1[3n+i,k] ----------------
__global__ __launch_bounds__(256) void k_reduceT(const float* __restrict__ coords,
                                                 const float* __restrict__ W1,
                                                 float* __restrict__ partial) {
  float acc[72];
  #pragma unroll
  for (int t = 0; t < 72; ++t) acc[t] = 0.f;
  int idx = blockIdx.x * 256 + threadIdx.x;
  for (int n = idx; n < N_; n += 256 * 256) {
    float c0 = coords[n * 3 + 0], c1 = coords[n * 3 + 1], c2 = coords[n * 3 + 2];
    const float4* w4 = reinterpret_cast<const float4*>(W1 + (size_t)n * 24);
    #pragma unroll
    for (int i = 0; i < 3; ++i) {
      float4 wa = w4[i * 2 + 0], wb = w4[i * 2 + 1];
      float wv[8] = {wa.x, wa.y, wa.z, wa.w, wb.x, wb.y, wb.z, wb.w};
      #pragma unroll
      for (int k = 0; k < 8; ++k) {
        acc[i * 8 + k]      += c0 * wv[k];
        acc[24 + i * 8 + k] += c1 * wv[k];
        acc[48 + i * 8 + k] += c2 * wv[k];
      }
    }
  }
  #pragma unroll
  for (int t = 0; t < 72; ++t) {
    float v = acc[t];
    for (int off = 32; off > 0; off >>= 1) v += __shfl_down(v, off, 64);
    acc[t] = v;
  }
  __shared__ float sred[4][72];
  int lane = threadIdx.x & 63, wv_ = threadIdx.x >> 6;
  if (lane == 0) {
    #pragma unroll
    for (int t = 0; t < 72; ++t) sred[wv_][t] = acc[t];
  }
  __syncthreads();
  if (threadIdx.x < 72) {
    int t = threadIdx.x;
    partial[blockIdx.x * 72 + t] = sred[0][t] + sred[1][t] + sred[2][t] + sred[3][t];
  }
}

// ---------------- per-batch: finalize T, rotation matrices, MLP head ----------------
__global__ __launch_bounds__(128) void k_batch(const float* __restrict__ partial,
                                               const float* __restrict__ rows,
                                               const float* __restrict__ b1,
                                               const float* __restrict__ Wh,
                                               const float* __restrict__ bh,
                                               float* __restrict__ hbuf,
                                               float* __restrict__ Rbuf) {
  __shared__ float T[72];
  int tid = threadIdx.x;
  if (tid < 72) {
    double s = 0.0;
    for (int i = 0; i < 256; ++i) s += (double)partial[i * 72 + tid];
    T[tid] = (float)s;
  }
  __syncthreads();
  if (tid < B_) {
    int b = tid;
    float al = rows[b * 3 + 0], be = rows[b * 3 + 1], ga = rows[b * 3 + 2];
    float sa, ca, sb, cb, sg, cg;
    sincosf(al, &sa, &ca); sincosf(be, &sb, &cb); sincosf(ga, &sg, &cg);
    float R[3][3];
    R[0][0] = ca * cb * cg - sa * sg; R[0][1] = -ca * cb * sg - sa * cg; R[0][2] = ca * sb;
    R[1][0] = sa * cb * cg + ca * sg; R[1][1] = -sa * cb * sg + ca * cg; R[1][2] = sa * sb;
    R[2][0] = -sb * cg;               R[2][1] = sb * sg;                 R[2][2] = cb;
    float h[8];
    #pragma unroll
    for (int k = 0; k < 8; ++k) {
      float z = b1[k];
      #pragma unroll
      for (int i = 0; i < 3; ++i)
        #pragma unroll
        for (int j = 0; j < 3; ++j)
          z += R[i][j] * T[(j * 3 + i) * 8 + k];
      h[k] = sinf(30.f * z);
    }
    for (int l = 0; l < 3; ++l) {
      float nh[8];
      #pragma unroll
      for (int k2 = 0; k2 < 8; ++k2) {
        float z = bh[l * 8 + k2];
        #pragma unroll
        for (int k1 = 0; k1 < 8; ++k1) z += h[k1] * Wh[l * 64 + k1 * 8 + k2];
        nh[k2] = sinf(z);
      }
      #pragma unroll
      for (int k = 0; k < 8; ++k) h[k] = nh[k];
    }
    #pragma unroll
    for (int k = 0; k < 8; ++k) hbuf[b * 8 + k] = h[k];
    #pragma unroll
    for (int i = 0; i < 3; ++i)
      #pragma unroll
      for (int j = 0; j < 3; ++j) Rbuf[b * 9 + i * 3 + j] = R[i][j];
  }
}

// ---------------- W5 transpose: W5T[n][k] = W5[k][n] ----------------
__global__ __launch_bounds__(256) void k_w5t(const float* __restrict__ W5, float* __restrict__ w5t) {
  int n = blockIdx.x * 256 + threadIdx.x;
  if (n >= N_) return;
  float v[8];
  #pragma unroll
  for (int k = 0; k < 8; ++k) v[k] = W5[(size_t)k * N_ + n];
  float4* dst = reinterpret_cast<float4*>(w5t + (size_t)n * 8);
  dst[0] = make_float4(v[0], v[1], v[2], v[3]);
  dst[1] = make_float4(v[4], v[5], v[6], v[7]);
}

// ---------------- direct scatter v2: block = (image, band, half); 4-pt unroll ----------------
__global__ __launch_bounds__(1024) void k_direct2(const float* __restrict__ coords,
                                                  const float* __restrict__ w5t,
                                                  const float* __restrict__ b5,
                                                  const float* __restrict__ hbuf,
                                                  const float* __restrict__ Rbuf,
                                                  const float* __restrict__ shifts,
                                                  float* __restrict__ tiles) {
  __shared__ float tile[32 * XSZ];     // 32 KB
  __shared__ float sp[16];
  int tid = threadIdx.x;
  int bid = blockIdx.x;
  int b = bid >> 4;
  int band = (bid >> 1) & 7;
  int half = bid & 1;
  int r0 = band << 5;
  if (tid < 6)       sp[tid] = Rbuf[b * 9 + tid] * 100.f;
  else if (tid < 8)  sp[tid] = 128.f - shifts[b * 2 + (tid - 6)];
  else if (tid < 16) sp[tid] = hbuf[b * 8 + (tid - 8)];
  for (int i = tid; i < 32 * XSZ; i += 1024) tile[i] = 0.f;
  __syncthreads();
  float A0 = sp[0], A1 = sp[1], A2 = sp[2];
  float A3 = sp[3], A4 = sp[4], A5 = sp[5];
  float bx = sp[6], by = sp[7];
  float h0 = sp[8], h1 = sp[9], h2 = sp[10], h3 = sp[11];
  float h4 = sp[12], h5 = sp[13], h6 = sp[14], h7 = sp[15];
  float ylo = (float)(r0 - 1), yhi = (float)(r0 + 32);
  const int nbeg = half * (N_ / 2), nend = nbeg + (N_ / 2);   // 100000, mult of 4
  for (int p0 = nbeg + tid * 4; p0 < nend; p0 += 4096) {
    // 4 points: 12 floats, 16B-aligned (p0 % 4 == 0)
    const float4* cp = reinterpret_cast<const float4*>(coords + (size_t)p0 * 3);
    float4 ca = cp[0], cb = cp[1], cc = cp[2];
    float pc[4][3] = {{ca.x, ca.y, ca.z}, {ca.w, cb.x, cb.y},
                      {cb.z, cb.w, cc.x}, {cc.y, cc.z, cc.w}};
    #pragma unroll
    for (int j = 0; j < 4; ++j) {
      float c0 = pc[j][0], c1 = pc[j][1], c2 = pc[j][2];
      float px = fmaf(A0, c0, fmaf(A1, c1, fmaf(A2, c2, bx)));
      float py = fmaf(A3, c0, fmaf(A4, c1, fmaf(A5, c2, by)));
      if (py >= ylo && py < yhi && px >= -1.f && px < 256.f) {
        int n = p0 + j;
        const float4* w = reinterpret_cast<const float4*>(w5t + (size_t)n * 8);
        float4 wa = w[0], wb = w[1];
        float delta = b5[n];
        delta = fmaf(h0, wa.x, delta); delta = fmaf(h1, wa.y, delta);
        delta = fmaf(h2, wa.z, delta); delta = fmaf(h3, wa.w, delta);
        delta = fmaf(h4, wb.x, delta); delta = fmaf(h5, wb.y, delta);
        delta = fmaf(h6, wb.z, delta); delta = fmaf(h7, wb.w, delta);
        float x0f = floorf(px), y0f = floorf(py);
        float fx = px - x0f, fy = py - y0f;
        int x0 = (int)x0f;
        int r = (int)y0f - r0;           // in [-1, 31]
        float wy0 = (1.f - fy) * delta, wy1 = fy * delta;
        bool xl = (x0 >= 0), xr = (x0 <= 254);
        if (r >= 0) {
          int c0i = r * XSZ + x0;
          if (xl) atomicAdd(&tile[c0i], (1.f - fx) * wy0);
          if (xr) atomicAdd(&tile[c0i + 1], fx * wy0);
        }
        if (r < 31) {
          int c1i = (r + 1) * XSZ + x0;
          if (xl) atomicAdd(&tile[c1i], (1.f - fx) * wy1);
          if (xr) atomicAdd(&tile[c1i + 1], fx * wy1);
        }
      }
    }
  }
  __syncthreads();
  float* dst = tiles + (size_t)bid * 8192;
  for (int i = tid; i < 8192; i += 1024) dst[i] = tile[i];
}

// ---------------- merge the two half-tiles into img ----------------
__global__ __launch_bounds__(256) void k_merge(const float* __restrict__ tiles,
                                               float* __restrict__ img) {
  int i = blockIdx.x * 256 + threadIdx.x;     // [0, 2M)
  int b = i >> 16;
  int y = (i >> 8) & 255;
  int x = i & 255;
  int band = y >> 5, r = y & 31;
  size_t t0 = ((size_t)((b << 4) + (band << 1))) * 8192 + r * 256 + x;
  img[i] = tiles[t0] + tiles[t0 + 8192];
}

// ---------------- separable Gaussian blur (zero-padded SAME) ----------------
__device__ __forceinline__ float bwv(int i) {
  const float bw[7] = {0.004433048f, 0.054005582f, 0.242036226f, 0.399050280f,
                       0.242036226f, 0.054005582f, 0.004433048f};
  return bw[i];
}

__global__ __launch_bounds__(256) void k_blurV(const float* __restrict__ in, float* __restrict__ out) {
  int i = blockIdx.x * 256 + threadIdx.x;
  int x = i & 255;
  int y = (i >> 8) & 255;
  const float* p = in + (i & ~65535);
  float s = 0.f;
  #pragma unroll
  for (int d = -3; d <= 3; ++d) {
    int yy = y + d;
    if ((unsigned)yy < XSZ) s += bwv(d + 3) * p[(yy << 8) + x];
  }
  out[i] = s;
}

__global__ __launch_bounds__(256) void k_blurH(const float* __restrict__ in, float* __restrict__ out) {
  int i = blockIdx.x * 256 + threadIdx.x;
  int x = i & 255;
  float s = 0.f;
  #pragma unroll
  for (int d = -3; d <= 3; ++d) {
    int xx = x + d;
    if ((unsigned)xx < XSZ) s += bwv(d + 3) * in[i + d];
  }
  out[i] = s;
}

// ---------------- FFT helpers: 256-pt, SoA in LDS, stride PADS ----------------
__device__ __forceinline__ void fft_dif_fwd(float* re, float* im, const float2* tw, int P, int tid) {
  for (int s = 7; s >= 0; --s) {
    __syncthreads();
    int half = 1 << s;
    for (int q = tid; q < (P << 7); q += 256) {
      int p = q >> 7, k = q & 127;
      int j = k & (half - 1);
      int i0 = ((k >> s) << (s + 1)) | j;
      int i1 = i0 + half;
      float* rp = re + p * PADS; float* ip = im + p * PADS;
      float ar = rp[i0], ai = ip[i0], br = rp[i1], bi = ip[i1];
      rp[i0] = ar + br; ip[i0] = ai + bi;
      float tr = ar - br, ti = ai - bi;
      float2 w = tw[j << (7 - s)];
      rp[i1] = tr * w.x - ti * w.y;
      ip[i1] = tr * w.y + ti * w.x;
    }
  }
  __syncthreads();
}

__device__ __forceinline__ void fft_dit_inv(float* re, float* im, const float2* tw, int P, int tid) {
  for (int s = 0; s <= 7; ++s) {
    __syncthreads();
    int half = 1 << s;
    for (int q = tid; q < (P << 7); q += 256) {
      int p = q >> 7, k = q & 127;
      int j = k & (half - 1);
      int i0 = ((k >> s) << (s + 1)) | j;
      int i1 = i0 + half;
      float* rp = re + p * PADS; float* ip = im + p * PADS;
      float2 w = tw[j << (7 - s)];               // conj -> (w.x, -w.y)
      float br = rp[i1], bi = ip[i1];
      float tr = br * w.x + bi * w.y;
      float ti = bi * w.x - br * w.y;
      float ar = rp[i0], ai = ip[i0];
      rp[i0] = ar + tr; ip[i0] = ai + ti;
      rp[i1] = ar - tr; ip[i1] = ai - ti;
    }
  }
  __syncthreads();
}

__device__ __forceinline__ void tw_init(float2* tw, int tid) {
  for (int k = tid; k < 128; k += 256) {
    float s_, c_;
    sincosf(-6.2831853071795864769f * (float)k / 256.0f, &s_, &c_);
    tw[k] = make_float2(c_, s_);
  }
}

// F1: row FFT (over x), DIF, store transposed: Fc[b][i][y] holds kx=rev8(i)
__global__ __launch_bounds__(256) void k_fft1(const float* __restrict__ img, float2* __restrict__ Fc) {
  __shared__ float re[16 * PADS], im[16 * PADS];
  __shared__ float2 tw[128];
  int tid = threadIdx.x;
  int b = blockIdx.x >> 4;
  int y0 = (blockIdx.x & 15) << 4;
  tw_init(tw, tid);
  const float* src = img + (size_t)b * 65536 + (size_t)y0 * 256;
  for (int q = tid; q < 4096; q += 256) {
    int j = q >> 8, x = q & 255;
    re[j * PADS + x] = src[j * 256 + x];
    im[j * PADS + x] = 0.f;
  }
  fft_dif_fwd(re, im, tw, 16, tid);
  float2* dst = Fc + (size_t)b * 65536;
  for (int q = tid; q < 4096; q += 256) {
    int j = q & 15, i = q >> 4;
    dst[(size_t)i * 256 + y0 + j] = make_float2(re[j * PADS + i], im[j * PADS + i]);
  }
}

// F2: column FFT (over y) DIF fwd, * ctf_ext, DIT inverse; in-place on Fc rows
__global__ __launch_bounds__(256) void k_fft2(float2* __restrict__ Fc, const float* __restrict__ ctf) {
  __shared__ float re[4 * PADS], im[4 * PADS];
  __shared__ float2 tw[128];
  int tid = threadIdx.x;
  int b = blockIdx.x >> 6;
  int r0 = (blockIdx.x & 63) << 2;
  tw_init(tw, tid);
  float2* base = Fc + (size_t)b * 65536 + (size_t)r0 * 256;
  for (int q = tid; q < 1024; q += 256) {
    int p = q >> 8, y = q & 255;
    float2 v = base[p * 256 + y];
    re[p * PADS + y] = v.x; im[p * PADS + y] = v.y;
  }
  fft_dif_fwd(re, im, tw, 4, tid);
  for (int q = tid; q < 1024; q += 256) {
    int p = q >> 8, iy = q & 255;
    int kx = rev8(r0 + p), ky = rev8(iy);
    float c;
    if (kx <= 128) c = ctf[((size_t)b * 256 + ky) * 129 + kx];
    else           c = ctf[((size_t)b * 256 + ((256 - ky) & 255)) * 129 + (256 - kx)];
    re[p * PADS + iy] *= c; im[p * PADS + iy] *= c;
  }
  fft_dit_inv(re, im, tw, 4, tid);
  for (int q = tid; q < 1024; q += 256) {
    int p = q >> 8, y = q & 255;
    base[p * 256 + y] = make_float2(re[p * PADS + y], im[p * PADS + y]);
  }
}

// F3: inverse row FFT (over kx). Rows of Fc are already bitrev-ordered in kx -> DIT direct.
__global__ __launch_bounds__(256) void k_fft3(const float2* __restrict__ Fc, float* __restrict__ out) {
  __shared__ float re[16 * PADS], im[16 * PADS];
  __shared__ float2 tw[128];
  int tid = threadIdx.x;
  int b = blockIdx.x >> 4;
  int y0 = (blockIdx.x & 15) << 4;
  tw_init(tw, tid);
  const float2* src = Fc + (size_t)b * 65536;
  for (int q = tid; q < 4096; q += 256) {
    int j = q & 15, r = q >> 4;
    float2 v = src[(size_t)r * 256 + y0 + j];
    re[j * PADS + r] = v.x; im[j * PADS + r] = v.y;
  }
  fft_dit_inv(re, im, tw, 16, tid);
  float* dst = out + (size_t)b * 65536 + (size_t)y0 * 256;
  for (int q = tid; q < 4096; q += 256) {
    int j = q >> 8, x = q & 255;
    dst[j * 256 + x] = re[j * PADS + x] * (1.f / 65536.f);
  }
}

extern "C" void kernel_launch(void* const* d_in, const int* in_sizes, int n_in,
                              void* d_out, int out_size, void* d_ws, size_t ws_size,
                              hipStream_t stream) {
  const float* rows   = (const float*)d_in[0];
  const float* shifts = (const float*)d_in[1];
  const float* coords = (const float*)d_in[2];
  const float* W1     = (const float*)d_in[3];
  const float* b1     = (const float*)d_in[4];
  const float* Wh     = (const float*)d_in[5];
  const float* bh     = (const float*)d_in[6];
  const float* W5     = (const float*)d_in[7];
  const float* b5     = (const float*)d_in[8];
  const float* ctf    = (const float*)d_in[9];
  float* out = (float*)d_out;
  char* ws = (char*)d_ws;

  float*    partial = (float*)(ws + OFF_PART);
  float*    hbuf    = (float*)(ws + OFF_H);
  float*    Rbuf    = (float*)(ws + OFF_R);
  float*    img     = (float*)(ws + OFF_IMG);
  float*    tiles   = (float*)(ws + OFF_TILES);
  float*    w5t     = (float*)(ws + OFF_W5T);
  float*    tmp     = (float*)(ws + OFF_TMP);
  float2*   Fc      = (float2*)(ws + OFF_FC);

  k_reduceT<<<256, 256, 0, stream>>>(coords, W1, partial);
  k_batch<<<1, 128, 0, stream>>>(partial, rows, b1, Wh, bh, hbuf, Rbuf);
  k_w5t<<<(N_ + 255) / 256, 256, 0, stream>>>(W5, w5t);
  k_direct2<<<512, 1024, 0, stream>>>(coords, w5t, b5, hbuf, Rbuf, shifts, tiles);
  k_merge<<<B_ * XSZ * XSZ / 256, 256, 0, stream>>>(tiles, img);
  k_blurV<<<B_ * XSZ * XSZ / 256, 256, 0, stream>>>(img, tmp);
  k_blurH<<<B_ * XSZ * XSZ / 256, 256, 0, stream>>>(tmp, img);
  k_fft1<<<B_ * 16, 256, 0, stream>>>(img, Fc);
  k_fft2<<<B_ * 64, 256, 0, stream>>>(Fc, ctf);
  k_fft3<<<B_ * 16, 256, 0, stream>>>(Fc, out);
}